// Round 9
// baseline (226.326 us; speedup 1.0000x reference)
//
#include <hip/hip_runtime.h>

#define N_NODES 100000
#define BSH 9                      // 512 nodes per bucket
#define NBKT ((N_NODES + 511) >> BSH)   // 196
#define CH 7168                    // items per partition chunk (56KB LDS stage)

typedef unsigned int u32;
typedef unsigned short u16;
typedef __attribute__((ext_vector_type(8))) short s8v;   // 8 bf16 (4 VGPRs)
typedef __attribute__((ext_vector_type(4))) float f4v;   // 4 f32 acc

static __device__ __forceinline__ u16 f2bf(float f) {  // round-nearest-even
    union { float f; u32 u; } c; c.f = f;
    u32 r = (c.u + 0x7fffu + ((c.u >> 16) & 1u)) >> 16;
    return (u16)r;
}
static __device__ __forceinline__ float bf2f_u(u16 h) {
    union { u32 u; float f; } c; c.u = ((u32)h) << 16;
    return c.f;
}
static __device__ __forceinline__ void acc2(u32 p, float& a, float& b) {
    union { u32 u; float f; } lo, hi;
    lo.u = p << 16;
    hi.u = p & 0xffff0000u;
    a += lo.f;
    b += hi.f;
}
static __device__ __forceinline__ void acc8(uint4 p, float* a) {
    acc2(p.x, a[0], a[1]); acc2(p.y, a[2], a[3]);
    acc2(p.z, a[4], a[5]); acc2(p.w, a[6], a[7]);
}

// ============ CSR build, bucketed ============
// item e in [0,E) = edge (src[e],dst[e]); e in [E,E+N) = self-loop (v,v).

__global__ __launch_bounds__(256) void coarsehist_k(const int* __restrict__ dst,
        int* __restrict__ ccount, int E, int TOT) {
    __shared__ int hist[256];
    hist[threadIdx.x] = 0;
    __syncthreads();
    int base = blockIdx.x * CH;
    int cnt = min(CH, TOT - base);
    for (int i = threadIdx.x; i < cnt; i += 256) {
        int e = base + i;
        int d = (e < E) ? dst[e] : e - E;
        atomicAdd(&hist[d >> BSH], 1);
    }
    __syncthreads();
    if (hist[threadIdx.x]) atomicAdd(&ccount[threadIdx.x], hist[threadIdx.x]);
}

// single block: scan 196 coarse counts -> cbase[0..NBKT], bcur, offsets[N]
__global__ __launch_bounds__(256) void coarsescan_k(const int* __restrict__ ccount,
        int* __restrict__ cbase, int* __restrict__ bcur, int* __restrict__ offsets) {
    __shared__ int ps[256];
    int t = threadIdx.x;
    int c = (t < NBKT) ? ccount[t] : 0;
    ps[t] = c;
    __syncthreads();
    for (int off = 1; off < 256; off <<= 1) {
        int val = ps[t];
        int add = (t >= off) ? ps[t - off] : 0;
        __syncthreads();
        ps[t] = val + add;
        __syncthreads();
    }
    int incl = ps[t], excl = incl - c;
    if (t < NBKT) cbase[t] = excl;
    bcur[t] = (t < NBKT) ? excl : incl;   // t>=NBKT: total (unused)
    if (t == NBKT - 1) cbase[NBKT] = incl;
    if (t == 255) offsets[N_NODES] = ps[255];
}

// chunked LDS counting-sort partition: items -> bktBuf grouped by bucket,
// each (block,bucket) run written contiguously (line-efficient, single-XCD).
__global__ __launch_bounds__(256) void partition_k(const int* __restrict__ src,
        const int* __restrict__ dst, int* __restrict__ bcur,
        uint2* __restrict__ bktBuf, int E, int TOT) {
    __shared__ int hist[256];
    __shared__ int lbase[256];
    __shared__ int gbase[256];
    __shared__ int ps[256];
    __shared__ uint2 stage[CH];
    int t = threadIdx.x;
    int base = blockIdx.x * CH;
    int cnt = min(CH, TOT - base);
    hist[t] = 0;
    __syncthreads();
    // pass A: bucket counts
    for (int i = t; i < cnt; i += 256) {
        int e = base + i;
        int d = (e < E) ? dst[e] : e - E;
        atomicAdd(&hist[d >> BSH], 1);
    }
    __syncthreads();
    // scan -> local bases; reserve global runs
    ps[t] = hist[t];
    __syncthreads();
    for (int off = 1; off < 256; off <<= 1) {
        int val = ps[t];
        int add = (t >= off) ? ps[t - off] : 0;
        __syncthreads();
        ps[t] = val + add;
        __syncthreads();
    }
    lbase[t] = ps[t] - hist[t];
    gbase[t] = atomicAdd(&bcur[t], hist[t]);
    hist[t] = 0;                 // reuse as local cursor
    __syncthreads();
    // pass B: stage bucket-sorted in LDS
    for (int i = t; i < cnt; i += 256) {
        int e = base + i;
        int s, d;
        if (e < E) { s = src[e]; d = dst[e]; }
        else       { s = d = e - E; }
        int b = d >> BSH;
        int lpos = lbase[b] + atomicAdd(&hist[b], 1);
        stage[lpos] = make_uint2((u32)s, (u32)d);
    }
    __syncthreads();
    // pass C: contiguous run writes
    for (int i = t; i < cnt; i += 256) {
        uint2 p = stage[i];
        int b = (int)p.y >> BSH;
        bktBuf[gbase[b] + (i - lbase[b])] = p;
    }
}

// one block per bucket: local deg histogram+scan -> offsets, dinv; then
// scatter srt_src inside the block-exclusive window.
__global__ __launch_bounds__(256) void buildfill_k(const int* __restrict__ cbase,
        const uint2* __restrict__ bktBuf, int* __restrict__ offsets,
        float* __restrict__ dinv, int* __restrict__ srt_src) {
    __shared__ int hist[512];
    __shared__ int hscan[512];
    __shared__ int cur[512];
    __shared__ int ps[256];
    int t = threadIdx.x;
    int b = blockIdx.x;
    int v0 = b << BSH;
    int nv = min(512, N_NODES - v0);
    hist[t] = 0; hist[t + 256] = 0;
    cur[t] = 0;  cur[t + 256] = 0;
    __syncthreads();
    int beg = cbase[b], endi = cbase[b + 1];
    for (int i = beg + t; i < endi; i += 256)
        atomicAdd(&hist[(int)bktBuf[i].y - v0], 1);
    __syncthreads();
    // exclusive scan of hist[0..511] (pairs + Hillis-Steele over 256)
    int a = hist[2 * t], bb = hist[2 * t + 1];
    int own = a + bb;
    ps[t] = own;
    __syncthreads();
    for (int off = 1; off < 256; off <<= 1) {
        int val = ps[t];
        int add = (t >= off) ? ps[t - off] : 0;
        __syncthreads();
        ps[t] = val + add;
        __syncthreads();
    }
    int excl2 = ps[t] - own;
    hscan[2 * t] = excl2;
    hscan[2 * t + 1] = excl2 + a;
    __syncthreads();
    // offsets + dinv (hist includes the self-loop -> deg+1)
    for (int j = t; j < nv; j += 256) {
        offsets[v0 + j] = beg + hscan[j];
        dinv[v0 + j] = rsqrtf((float)hist[j]);
    }
    // scatter within [beg, endi) — block-exclusive window
    for (int i = beg + t; i < endi; i += 256) {
        uint2 p = bktBuf[i];
        int j = (int)p.y - v0;
        int pos = atomicAdd(&cur[j], 1);
        srt_src[beg + hscan[j] + pos] = (int)p.x;
    }
}

// ============ GEMM1 (MFMA): h1b[N,64](bf16) = dinv[row] * (x[N,128] @ W1) ====

static __device__ __forceinline__ void split8(const float* __restrict__ xp,
                                              s8v& hi, s8v& lo) {
    float4 v0 = *(const float4*)xp;
    float4 v1 = *(const float4*)(xp + 4);
    float xv[8] = {v0.x, v0.y, v0.z, v0.w, v1.x, v1.y, v1.z, v1.w};
#pragma unroll
    for (int j = 0; j < 8; ++j) {
        u16 h = f2bf(xv[j]);
        hi[j] = (short)h;
        lo[j] = (short)f2bf(xv[j] - bf2f_u(h));
    }
}

__global__ __launch_bounds__(256) void gemm1_k(const float* __restrict__ x,
                                               const float* __restrict__ W1,
                                               const float* __restrict__ dinv,
                                               u16* __restrict__ h1b) {
    // Bs[h][kstep][ct][(kgroup*16+col)*8+kk]
    __shared__ __attribute__((aligned(16))) short Bs[2][4][4][512];
    int t = threadIdx.x;
    for (int i = t; i < 128 * 64; i += 256) {
        int k = i >> 6, c = i & 63;
        float w = W1[i];
        u16 h = f2bf(w);
        u16 l = f2bf(w - bf2f_u(h));
        int ks = k >> 5, kg = (k >> 3) & 3, kk = k & 7;
        int ct = c >> 4, col = c & 15;
        int idx = (kg * 16 + col) * 8 + kk;
        Bs[0][ks][ct][idx] = (short)h;
        Bs[1][ks][ct][idx] = (short)l;
    }
    __syncthreads();

    int lane = t & 63;
    int rows0 = (blockIdx.x * 4 + (t >> 6)) * 32;
    if (rows0 >= N_NODES) return;

    f4v acc[2][4];
#pragma unroll
    for (int rt = 0; rt < 2; ++rt)
#pragma unroll
        for (int ct = 0; ct < 4; ++ct)
            acc[rt][ct] = (f4v){0.f, 0.f, 0.f, 0.f};

    int arow = lane & 15;
    int kgl = lane >> 4;
#pragma unroll
    for (int ks = 0; ks < 4; ++ks) {
        s8v bh[4], bl[4];
#pragma unroll
        for (int ct = 0; ct < 4; ++ct) {
            bh[ct] = *(const s8v*)&Bs[0][ks][ct][lane * 8];
            bl[ct] = *(const s8v*)&Bs[1][ks][ct][lane * 8];
        }
#pragma unroll
        for (int rt = 0; rt < 2; ++rt) {
            s8v ah, al;
            const float* xp = x + (size_t)(rows0 + rt * 16 + arow) * 128
                                + ks * 32 + kgl * 8;
            split8(xp, ah, al);
#pragma unroll
            for (int ct = 0; ct < 4; ++ct) {
                acc[rt][ct] = __builtin_amdgcn_mfma_f32_16x16x32_bf16(
                    ah, bh[ct], acc[rt][ct], 0, 0, 0);
                acc[rt][ct] = __builtin_amdgcn_mfma_f32_16x16x32_bf16(
                    ah, bl[ct], acc[rt][ct], 0, 0, 0);
                acc[rt][ct] = __builtin_amdgcn_mfma_f32_16x16x32_bf16(
                    al, bh[ct], acc[rt][ct], 0, 0, 0);
            }
        }
    }

#pragma unroll
    for (int rt = 0; rt < 2; ++rt) {
        int rbase = rows0 + rt * 16 + ((lane >> 4) << 2);
        float dv[4];
#pragma unroll
        for (int r = 0; r < 4; ++r) dv[r] = dinv[rbase + r];
#pragma unroll
        for (int ct = 0; ct < 4; ++ct) {
            int col = ct * 16 + (lane & 15);
#pragma unroll
            for (int r = 0; r < 4; ++r)
                h1b[(size_t)(rbase + r) * 64 + col] = f2bf(acc[rt][ct][r] * dv[r]);
        }
    }
}

// ============ layer2: h2b = dinv * (relu(dinv*agg + b1) @ W2) ============
// 2 nodes/wave, uint4 rows (8 lanes x 16B = 128B), software-pipelined
// depth-2 per node -> steady 4 gathers (4KB) in flight, uniform control flow.

#define L2_FETCH(F, V, P, EE) \
    if (P + 8 <= EE) { int s_ = srt_src[P + oc8]; F = rows4[s_ * 8 + f8]; \
                       V = true; P += 8; } else V = false;

__global__ __launch_bounds__(256) void layer2_k(const int* __restrict__ offsets,
        const int* __restrict__ srt_src, const float* __restrict__ dinv,
        const u16* __restrict__ h1b, const float* __restrict__ b1,
        const float* __restrict__ W2, u16* __restrict__ h2b) {
    __shared__ float W2s[64 * 32];
    __shared__ float b1s[64];
    for (int i = threadIdx.x; i < 64 * 32; i += 256) W2s[i] = W2[i];
    if (threadIdx.x < 64) b1s[threadIdx.x] = b1[threadIdx.x];
    __syncthreads();
    int lane = threadIdx.x & 63;
    int f8 = lane & 7, oc8 = lane >> 3;
    int v0 = blockIdx.x * 8 + (threadIdx.x >> 6) * 2;   // grid = N/8
    int v1 = v0 + 1;
    int p0 = offsets[v0], e0 = offsets[v1], e1 = offsets[v1 + 1];
    int p1 = e0;
    const uint4* rows4 = (const uint4*)h1b;             // row s = rows4 + s*8
    float a[8] = {0.f, 0.f, 0.f, 0.f, 0.f, 0.f, 0.f, 0.f};
    float c[8] = {0.f, 0.f, 0.f, 0.f, 0.f, 0.f, 0.f, 0.f};
    uint4 F0a, F0b, F1a, F1b;
    bool v0a, v0b, v1a, v1b;
    L2_FETCH(F0a, v0a, p0, e0);
    L2_FETCH(F1a, v1a, p1, e1);
    L2_FETCH(F0b, v0b, p0, e0);
    L2_FETCH(F1b, v1b, p1, e1);
    while (v0a || v1a) {
        uint4 C0 = F0a, C1 = F1a;
        bool c0 = v0a, c1 = v1a;
        F0a = F0b; v0a = v0b;
        F1a = F1b; v1a = v1b;
        L2_FETCH(F0b, v0b, p0, e0);
        L2_FETCH(F1b, v1b, p1, e1);
        if (c0) acc8(C0, a);
        if (c1) acc8(C1, c);
    }
    // per-lane tails (<8 edges left per node)
    if (p0 + oc8 < e0) {
        int s_ = srt_src[p0 + oc8];
        acc8(rows4[s_ * 8 + f8], a);
    }
    if (p1 + oc8 < e1) {
        int s_ = srt_src[p1 + oc8];
        acc8(rows4[s_ * 8 + f8], c);
    }
    // reduce over the 8 edge-slot groups (lane bits 3..5)
#pragma unroll
    for (int j = 0; j < 8; ++j) {
        a[j] += __shfl_xor(a[j], 8, 64);
        a[j] += __shfl_xor(a[j], 16, 64);
        a[j] += __shfl_xor(a[j], 32, 64);
        c[j] += __shfl_xor(c[j], 8, 64);
        c[j] += __shfl_xor(c[j], 16, 64);
        c[j] += __shfl_xor(c[j], 32, 64);
    }
    bool lo = (lane < 32);
    float dv = lo ? dinv[v0] : dinv[v1];
    float r[8];
#pragma unroll
    for (int j = 0; j < 8; ++j) {
        float tv = lo ? a[j] : c[j];
        r[j] = fmaxf(fmaf(dv, tv, b1s[8 * f8 + j]), 0.f);
    }
    int cc = lane & 31;
    float o = 0.f;
#pragma unroll
    for (int g = 0; g < 8; ++g) {
#pragma unroll
        for (int j = 0; j < 8; ++j)
            o = fmaf(__shfl(r[j], g, 8), W2s[(8 * g + j) * 32 + cc], o);
    }
    int vst = lo ? v0 : v1;
    h2b[vst * 32 + cc] = f2bf(dv * o);
}

// ============ layer3: out = relu(dinv*agg(h2b) + b2) @ Wfc + bfc ============
// 4 nodes/wave, uint4 rows (4 lanes x 16B = 64B), depth-1 rotating pipeline
// -> steady 4 gathers (64 rows) in flight.

#define L3_FETCH(F, V, P, EE) \
    if (P + 16 <= EE) { int s_ = srt_src[P + sl]; F = rows4[s_ * 4 + f4]; \
                        V = true; P += 16; } else V = false;

__global__ __launch_bounds__(256) void layer3_k(const int* __restrict__ offsets,
        const int* __restrict__ srt_src, const float* __restrict__ dinv,
        const u16* __restrict__ h2b, const float* __restrict__ b2,
        const float* __restrict__ Wfc, const float* __restrict__ bfc,
        float* __restrict__ out) {
    int lane = threadIdx.x & 63;
    int f4 = lane & 3, sl = lane >> 2;                  // 16 edge slots
    int vb = blockIdx.x * 16 + (threadIdx.x >> 6) * 4;  // grid = N/16
    int o0 = offsets[vb], o1 = offsets[vb + 1], o2 = offsets[vb + 2];
    int o3 = offsets[vb + 3], o4 = offsets[vb + 4];
    int p0 = o0, e0 = o1, p1 = o1, e1 = o2, p2 = o2, e2 = o3, p3 = o3, e3 = o4;
    const uint4* rows4 = (const uint4*)h2b;             // row s = rows4 + s*4
    float A[8] = {0.f, 0.f, 0.f, 0.f, 0.f, 0.f, 0.f, 0.f};
    float B[8] = {0.f, 0.f, 0.f, 0.f, 0.f, 0.f, 0.f, 0.f};
    float C[8] = {0.f, 0.f, 0.f, 0.f, 0.f, 0.f, 0.f, 0.f};
    float D[8] = {0.f, 0.f, 0.f, 0.f, 0.f, 0.f, 0.f, 0.f};
    uint4 F0, F1, F2, F3;
    bool g0, g1, g2, g3;
    L3_FETCH(F0, g0, p0, e0);
    L3_FETCH(F1, g1, p1, e1);
    L3_FETCH(F2, g2, p2, e2);
    L3_FETCH(F3, g3, p3, e3);
    while (g0 || g1 || g2 || g3) {
        uint4 T0 = F0, T1 = F1, T2 = F2, T3 = F3;
        bool h0 = g0, h1 = g1, h2 = g2, h3 = g3;
        L3_FETCH(F0, g0, p0, e0);
        L3_FETCH(F1, g1, p1, e1);
        L3_FETCH(F2, g2, p2, e2);
        L3_FETCH(F3, g3, p3, e3);
        if (h0) acc8(T0, A);
        if (h1) acc8(T1, B);
        if (h2) acc8(T2, C);
        if (h3) acc8(T3, D);
    }
    // per-lane tails (<16 edges left per node)
    if (p0 + sl < e0) { int s_ = srt_src[p0 + sl]; acc8(rows4[s_ * 4 + f4], A); }
    if (p1 + sl < e1) { int s_ = srt_src[p1 + sl]; acc8(rows4[s_ * 4 + f4], B); }
    if (p2 + sl < e2) { int s_ = srt_src[p2 + sl]; acc8(rows4[s_ * 4 + f4], C); }
    if (p3 + sl < e3) { int s_ = srt_src[p3 + sl]; acc8(rows4[s_ * 4 + f4], D); }
    // reduce over the 16 edge-slot groups (lane bits 2..5)
#pragma unroll
    for (int j = 0; j < 8; ++j) {
        A[j] += __shfl_xor(A[j], 4, 64);  A[j] += __shfl_xor(A[j], 8, 64);
        A[j] += __shfl_xor(A[j], 16, 64); A[j] += __shfl_xor(A[j], 32, 64);
        B[j] += __shfl_xor(B[j], 4, 64);  B[j] += __shfl_xor(B[j], 8, 64);
        B[j] += __shfl_xor(B[j], 16, 64); B[j] += __shfl_xor(B[j], 32, 64);
        C[j] += __shfl_xor(C[j], 4, 64);  C[j] += __shfl_xor(C[j], 8, 64);
        C[j] += __shfl_xor(C[j], 16, 64); C[j] += __shfl_xor(C[j], 32, 64);
        D[j] += __shfl_xor(D[j], 4, 64);  D[j] += __shfl_xor(D[j], 8, 64);
        D[j] += __shfl_xor(D[j], 16, 64); D[j] += __shfl_xor(D[j], 32, 64);
    }
    float dv0 = dinv[vb], dv1 = dinv[vb + 1], dv2 = dinv[vb + 2], dv3 = dinv[vb + 3];
    float pr0 = 0.f, pr1 = 0.f, pr2 = 0.f, pr3 = 0.f;
#pragma unroll
    for (int j = 0; j < 8; ++j) {
        int k = 8 * f4 + j;
        float w = Wfc[k], g = b2[k];
        pr0 += fmaxf(fmaf(dv0, A[j], g), 0.f) * w;
        pr1 += fmaxf(fmaf(dv1, B[j], g), 0.f) * w;
        pr2 += fmaxf(fmaf(dv2, C[j], g), 0.f) * w;
        pr3 += fmaxf(fmaf(dv3, D[j], g), 0.f) * w;
    }
    pr0 += __shfl_xor(pr0, 1, 64); pr0 += __shfl_xor(pr0, 2, 64);
    pr1 += __shfl_xor(pr1, 1, 64); pr1 += __shfl_xor(pr1, 2, 64);
    pr2 += __shfl_xor(pr2, 1, 64); pr2 += __shfl_xor(pr2, 2, 64);
    pr3 += __shfl_xor(pr3, 1, 64); pr3 += __shfl_xor(pr3, 2, 64);
    if (lane == 0) {
        float bb = bfc[0];
        out[vb + 0] = pr0 + bb;
        out[vb + 1] = pr1 + bb;
        out[vb + 2] = pr2 + bb;
        out[vb + 3] = pr3 + bb;
    }
}

// ============ launch ============

extern "C" void kernel_launch(void* const* d_in, const int* in_sizes, int n_in,
                              void* d_out, int out_size, void* d_ws, size_t ws_size,
                              hipStream_t stream) {
    const float* x   = (const float*)d_in[0];
    const int*   ei  = (const int*)d_in[1];
    const float* W1  = (const float*)d_in[2];
    const float* b1  = (const float*)d_in[3];
    const float* W2  = (const float*)d_in[4];
    const float* b2  = (const float*)d_in[5];
    const float* Wfc = (const float*)d_in[6];
    const float* bfc = (const float*)d_in[7];
    float* out = (float*)d_out;

    const int E = in_sizes[1] / 2;
    const int TOT = E + N_NODES;
    const int* src = ei;
    const int* dst = ei + E;

    // workspace layout (ints)
    int*   ccount  = (int*)d_ws;                   // 256
    int*   cbase   = ccount + 256;                 // 256 (NBKT+1 used)
    int*   bcur    = cbase + 256;                  // 256
    int*   offsets = bcur + 256;                   // N+1
    int*   srt_src = offsets + N_NODES + 1;        // TOT
    size_t bb_off  = (size_t)(srt_src - (int*)d_ws) + TOT;
    bb_off = (bb_off + 1) & ~(size_t)1;            // 8B-align for uint2
    uint2* bktBuf  = (uint2*)((int*)d_ws + bb_off);        // TOT uint2
    float* dinv    = (float*)((int*)d_ws + bb_off + 2 * (size_t)TOT);  // N
    u16*   h1b     = (u16*)(dinv + N_NODES);       // N*64 bf16
    u16*   h2b     = h1b + (size_t)N_NODES * 64;   // N*32 bf16

    const int NCH = (TOT + CH - 1) / CH;

    hipMemsetAsync(ccount, 0, 256 * sizeof(int), stream);
    coarsehist_k<<<NCH, 256, 0, stream>>>(dst, ccount, E, TOT);
    coarsescan_k<<<1, 256, 0, stream>>>(ccount, cbase, bcur, offsets);
    partition_k<<<NCH, 256, 0, stream>>>(src, dst, bcur, bktBuf, E, TOT);
    buildfill_k<<<NBKT, 256, 0, stream>>>(cbase, bktBuf, offsets, dinv, srt_src);

    const int GB1 = (N_NODES / 32 + 3) / 4;   // 782 blocks x 4 waves x 32 rows
    gemm1_k<<<GB1, 256, 0, stream>>>(x, W1, dinv, h1b);

    layer2_k<<<N_NODES / 8, 256, 0, stream>>>(offsets, srt_src, dinv, h1b, b1, W2, h2b);
    layer3_k<<<N_NODES / 16, 256, 0, stream>>>(offsets, srt_src, dinv, h2b, b2, Wfc,
                                               bfc, out);
}